// Round 9
// baseline (405.638 us; speedup 1.0000x reference)
//
#include <hip/hip_runtime.h>
#include <hip/hip_bf16.h>

// GCN: N=50000, E=800000, hidden 64, 5 convs (relu on first 4).
// f32 tensors, int32 edge_index, f32 d_out[N].  ws_size in [19.8, 26.0) MB.
// r26: 6+ waves/SIMD WITHOUT register-W. r22/r24/r25 all spilled the same way:
// any +32-reg W array at reduced cap -> allocator dumps it to scratch (VGPR 40,
// WRITE 57-84MB). r24/r25 proved occupancy reaches 61% and VALU stays 17% =>
// memory-stall bound, occupancy is the right lever. Fix: W lives in LDS as
// PACKED bf16 pairs (8KB, from k_pack), loaded once per block; body = the lean
// r21 44-VGPR core. LDS 16.9KB -> 6+ blocks/CU; no wbf regs -> no spill. W read
// = 32 ds_read_b32/node (2-way bank = free, ~5us/conv port time, overlappable).
// r18's W-LDS failure was halved waves, not LDS reads — waves stay at full count.
// gconv1 same at (256,8); gconv_z/k_out/CSR = r21 verbatim.
// Tripwires: conv WRITE_SIZE ~6.3MB, VGPR 50-70, occ >=55%.
// Workspace (~19.1 MB): gA bf16[N*64] | gB bf16[N*64] | xt f32x4[N] | bucket u16[E]
//   | staging u32[E] | row_start i32[N+1] | dinv f32[N] | zg f32[N] | wpk u32[3*2048]
//   | bktcnt i32[256] | ticket i32 | bktbase i32[257] | bcur i32[256]

#define TPB 256
#define EPT 8                    // edges per thread in k_bktcnt / k_bin
#define CHUNK (TPB * EPT)        // 2048 edges per block
typedef __hip_bfloat16 bf16;
#define B2F __bfloat162float

__global__ void k_zero_b(int* __restrict__ bktcnt, int* __restrict__ ticket) {
    bktcnt[threadIdx.x] = 0;
    if (threadIdx.x == 0) *ticket = 0;
}

// RN-to-bf16 pack of two f32 into one u32 (lo in [15:0], hi in [31:16]).
__device__ __forceinline__ unsigned pk_bf2(float lo, float hi) {
    unsigned a = __float_as_uint(lo);
    unsigned b = __float_as_uint(hi);
    a = (a + 0x7fffu + ((a >> 16) & 1u)) >> 16;
    b = (b + 0x7fffu + ((b >> 16) & 1u)) & 0xffff0000u;
    return b | (a & 0xffffu);
}

// Pre-pack W_h (3 x 64 x 64 f32) -> wpk[l][k2][j] = bf16pair(W[2k2][j], W[2k2+1][j]).
__global__ __launch_bounds__(TPB) void k_pack(const float* __restrict__ Wh,
                                              unsigned* __restrict__ wpk) {
    int t = blockIdx.x * blockDim.x + threadIdx.x;
    if (t >= 3 * 2048) return;
    int l = t >> 11, idx = t & 2047;
    int k2 = idx >> 6, j = idx & 63;
    const float* W = Wh + l * 4096;
    wpk[t] = pk_bf2(W[(2 * k2) * 64 + j], W[(2 * k2 + 1) * 64 + j]);
}

// Per-bucket (dst>>8) edge counts via LDS histogram; LAST block (ticket) also
// performs the 256-wide exclusive scan -> bktbase[257], bcur (fuses k_bktscan).
__global__ __launch_bounds__(TPB) void k_bktcnt(
    const int* __restrict__ dst, int* __restrict__ bktcnt, int* __restrict__ ticket,
    int* __restrict__ bktbase, int* __restrict__ bcur, int E, int n) {
    __shared__ int h[256];
    __shared__ int lastFlag;
    int tid = threadIdx.x;
    h[tid] = 0;
    __syncthreads();
    int e0 = blockIdx.x * CHUNK;
#pragma unroll
    for (int u = 0; u < EPT; ++u) {
        int e = e0 + u * TPB + tid;
        if (e < E) {
            int d = dst[e];
            if ((unsigned)d < (unsigned)n) atomicAdd(&h[d >> 8], 1);
        }
    }
    __syncthreads();
    if (h[tid]) atomicAdd(&bktcnt[tid], h[tid]);
    __threadfence();                               // counts visible before ticket
    __syncthreads();
    if (tid == 0) lastFlag = (atomicAdd(ticket, 1) == (int)gridDim.x - 1);
    __syncthreads();
    if (!lastFlag) return;                         // block-uniform exit
    // last block: coherent read of final counts, then scan (reuse h as buffer)
    int v = atomicAdd(&bktcnt[tid], 0);
    h[tid] = v;
    __syncthreads();
    for (int off = 1; off < 256; off <<= 1) {
        int u2 = (tid >= off) ? h[tid - off] : 0;
        __syncthreads();
        h[tid] += u2;
        __syncthreads();
    }
    int excl = h[tid] - v;
    bktbase[tid] = excl;
    bcur[tid] = excl;
    if (tid == 255) bktbase[256] = h[tid];
}

// Pass 1: bin edges by dst>>8 into staging (record = src | (dst&255)<<16).
__global__ __launch_bounds__(TPB) void k_bin(
    const int* __restrict__ src, const int* __restrict__ dst,
    int* __restrict__ bcur, unsigned* __restrict__ staging, int E, int n) {
    __shared__ int hcnt[256];
    __shared__ int hbase[256];
    int tid = threadIdx.x;
    int e0 = blockIdx.x * CHUNK;
    hcnt[tid] = 0;
    __syncthreads();

    int eb[EPT];
    unsigned rec[EPT];
#pragma unroll
    for (int u = 0; u < EPT; ++u) {
        int e = e0 + u * TPB + tid;
        eb[u] = -1;
        if (e < E) {
            int d = dst[e], s = src[e];
            if ((unsigned)d < (unsigned)n && (unsigned)s < (unsigned)n) {
                eb[u] = d >> 8;
                rec[u] = (unsigned)s | ((unsigned)(d & 255) << 16);
                atomicAdd(&hcnt[eb[u]], 1);
            }
        }
    }
    __syncthreads();
    int c = hcnt[tid];
    hbase[tid] = (c > 0) ? atomicAdd(&bcur[tid], c) : 0;
    hcnt[tid] = 0;
    __syncthreads();
#pragma unroll
    for (int u = 0; u < EPT; ++u) {
        if (eb[u] >= 0) {
            int r = atomicAdd(&hcnt[eb[u]], 1);
            int pos = hbase[eb[u]] + r;
            if ((unsigned)pos < (unsigned)E) staging[pos] = rec[u];  // replay-safe
        }
    }
}

// Pass 2: one block per bucket. Per-node histogram + prefix in LDS -> row_start,
// dinv, xt (=x*dinv), and record placement via LDS cursors.
__global__ __launch_bounds__(TPB) void k_unbin2(
    const unsigned* __restrict__ staging, const int* __restrict__ bktbase,
    const float* __restrict__ x, float4* __restrict__ xt,
    int* __restrict__ row_start, float* __restrict__ dinv,
    unsigned short* __restrict__ bucket, int E, int n) {
    __shared__ int cnt[256];
    __shared__ int scn[256];
    __shared__ int cur[256];
    int b = blockIdx.x, tid = threadIdx.x;
    int lo = bktbase[b], hi = bktbase[b + 1];
    lo = max(0, min(lo, E)); hi = max(lo, min(hi, E));

    cnt[tid] = 0;
    __syncthreads();
    for (int i = lo + tid; i < hi; i += TPB)
        atomicAdd(&cnt[(staging[i] >> 16) & 255], 1);
    __syncthreads();

    int v = cnt[tid];
    scn[tid] = v;
    __syncthreads();
    for (int off = 1; off < 256; off <<= 1) {
        int u = (tid >= off) ? scn[tid - off] : 0;
        __syncthreads();
        scn[tid] += u;
        __syncthreads();
    }
    int excl = scn[tid] - v;
    int base = min(lo + excl, E);
    cur[tid] = base;
    int d = (b << 8) + tid;
    if (d < n) {
        row_start[d] = base;
        float di = rsqrtf((float)v + 1.0f);    // +1 self-loop
        dinv[d] = di;
        float4 xv = ((const float4*)x)[d];     // x is f32[N][4], 16B aligned
        xv.x *= di; xv.y *= di; xv.z *= di; xv.w *= di;
        xt[d] = xv;                            // premultiplied raw features
        if (d == n - 1) row_start[n] = min(base + v, E);
    }
    __syncthreads();

    for (int i = lo + tid; i < hi; i += TPB) {
        unsigned r = staging[i];
        int t = (r >> 16) & 255;
        int pos = atomicAdd(&cur[t], 1);
        if ((unsigned)pos < (unsigned)E) bucket[pos] = (unsigned short)(r & 0xffffu);
    }
}

__device__ __forceinline__ void acc_oct(float* a, uint4 w) {
    a[0] += __uint_as_float(w.x << 16);
    a[1] += __uint_as_float(w.x & 0xffff0000u);
    a[2] += __uint_as_float(w.y << 16);
    a[3] += __uint_as_float(w.y & 0xffff0000u);
    a[4] += __uint_as_float(w.z << 16);
    a[5] += __uint_as_float(w.z & 0xffff0000u);
    a[6] += __uint_as_float(w.w << 16);
    a[7] += __uint_as_float(w.w & 0xffff0000u);
}

// OCT gather (r17/r21 proven shape): 8 edges per load instruction. Lane group
// grp=lane>>3 takes edge k+grp; lane i=lane&7 loads uint4 = 8 packed bf16 feats
// (8 lanes x 16B = full 128B row). Partials in registers; caller combines across
// groups via padded LDS rows.
__device__ __forceinline__ void agg_oct(const bf16* __restrict__ g,
                                        const unsigned short* __restrict__ bucket,
                                        int k0, int k1, int d, float* __restrict__ a,
                                        int lane, unsigned nm1, unsigned Em1) {
    int grp = lane >> 3, i = lane & 7;
#pragma unroll
    for (int m = 0; m < 8; ++m) a[m] = 0.f;
    if (grp == 0) {  // self term
        uint4 w = *(const uint4*)(g + (size_t)d * 64 + 8 * i);
        acc_oct(a, w);
    }
    for (int base = k0; base < k1; base += 64) {
        int cnt = min(64, k1 - base);
        int rec = bucket[min((unsigned)(base + lane), Em1)];  // coalesced u16 load
        int k = 0;
        for (; k + 16 <= cnt; k += 16) {                      // 16 edges, 2 oct loads
            unsigned s0 = min((unsigned)__shfl(rec, k + grp), nm1);
            unsigned s1 = min((unsigned)__shfl(rec, k + 8 + grp), nm1);
            uint4 w0 = *(const uint4*)(g + (size_t)s0 * 64 + 8 * i);
            uint4 w1 = *(const uint4*)(g + (size_t)s1 * 64 + 8 * i);
            acc_oct(a, w0);
            acc_oct(a, w1);
        }
        for (; k < cnt; k += 8) {                             // tail, predicated
            int e = k + grp;
            unsigned s = min((unsigned)__shfl(rec, min(e, 63)), nm1);
            uint4 w = *(const uint4*)(g + (size_t)s * 64 + 8 * i);
            if (e < cnt) acc_oct(a, w);
        }
    }
}

// Layer 1, aggregate-first: agg4[d] = xt[d] + sum xt[s]; 4-fma W_in transform;
// tail transform reads PACKED bf16 Wh0 from LDS (8KB, loaded once). Lean regs
// -> (256,8) for full occupancy.
__global__ __launch_bounds__(TPB, 8) void k_gconv1(
    const float4* __restrict__ xt, const float* __restrict__ dinv,
    const int* __restrict__ row_start, const unsigned short* __restrict__ bucket,
    const float* __restrict__ W_in, const float* __restrict__ b_in,
    const unsigned* __restrict__ wpk0, bf16* __restrict__ gOut, int n, int E) {
    __shared__ unsigned swpk[2048];      // 8 KB packed W column pairs
    __shared__ float sAct[4][64];
    int tid = threadIdx.x;
    {   // cooperative W stage: 512 uint4 / 256 threads = 2 each
        const uint4* wp4 = (const uint4*)wpk0;
        uint4* sp4 = (uint4*)swpk;
        sp4[tid] = wp4[tid];
        sp4[tid + 256] = wp4[tid + 256];
    }
    __syncthreads();

    int r = tid >> 6, j = tid & 63;
    unsigned nm1 = (unsigned)(n - 1);
    float win0 = W_in[0 * 64 + j], win1 = W_in[1 * 64 + j];
    float win2 = W_in[2 * 64 + j], win3 = W_in[3 * 64 + j];
    float bj = b_in[j];

    int nw = gridDim.x * 4;
    for (int d = blockIdx.x * 4 + r; d < n; d += nw) {      // wave-uniform loop
        float dd = dinv[d];
        int k0 = row_start[d], k1 = row_start[d + 1];
        k1 = min(k1, E); k0 = max(min(k0, k1), 0);

        float4 v = make_float4(0.f, 0.f, 0.f, 0.f);
        if (j == 0) v = xt[d];                              // self term
        for (int k = k0 + j; k < k1; k += 64) {
            unsigned s = min((unsigned)bucket[k], nm1);
            float4 t = xt[s];
            v.x += t.x; v.y += t.y; v.z += t.z; v.w += t.w;
        }
#pragma unroll
        for (int off = 1; off < 64; off <<= 1) {            // butterfly: all lanes
            v.x += __shfl_xor(v.x, off);
            v.y += __shfl_xor(v.y, off);
            v.z += __shfl_xor(v.z, off);
            v.w += __shfl_xor(v.w, off);
        }
        float dot = fmaf(v.x, win0, fmaf(v.y, win1, fmaf(v.z, win2, v.w * win3)));
        float act = fmaxf(fmaf(dd, dot, bj), 0.f);
        sAct[r][j] = act;                 // wave-local RAW -> lgkmcnt, no barrier

        float acc0 = 0.f, acc1 = 0.f;
        const float4* ap = (const float4*)&sAct[r][0];
#pragma unroll
        for (int k4 = 0; k4 < 16; ++k4) {
            float4 av = ap[k4];           // wave-uniform address -> broadcast b128
            unsigned wA = swpk[(2 * k4) * 64 + j];        // 2-way bank: free
            unsigned wB = swpk[(2 * k4 + 1) * 64 + j];
            acc0 = fmaf(av.x, __uint_as_float(wA << 16), acc0);
            acc1 = fmaf(av.y, __uint_as_float(wA & 0xffff0000u), acc1);
            acc0 = fmaf(av.z, __uint_as_float(wB << 16), acc0);
            acc1 = fmaf(av.w, __uint_as_float(wB & 0xffff0000u), acc1);
        }
        gOut[(size_t)d * 64 + j] = __float2bfloat16((acc0 + acc1) * dd);
    }
}

// Persistent fused middle layer: lean r21 body (no W regs); PACKED bf16 W in LDS
// (8KB), sVp padded-row combine. LDS 16.9KB, VGPR ~lean -> 6+ blocks/CU.
__global__ __launch_bounds__(TPB, 6) void k_gconv(
    const bf16* __restrict__ gIn, const float* __restrict__ dinv,
    const int* __restrict__ row_start, const unsigned short* __restrict__ bucket,
    const float* __restrict__ bias, const unsigned* __restrict__ wpk,
    bf16* __restrict__ gOut, int n, int E) {
    __shared__ unsigned swpk[2048];      // 8 KB packed W column pairs
    __shared__ float sVp[4][8][68];      // 8704 B, padded
    int tid = threadIdx.x;
    {   // cooperative W stage: 512 uint4 / 256 threads = 2 each
        const uint4* wp4 = (const uint4*)wpk;
        uint4* sp4 = (uint4*)swpk;
        sp4[tid] = wp4[tid];
        sp4[tid + 256] = wp4[tid + 256];
    }
    __syncthreads();

    int r = tid >> 6, j = tid & 63;
    int grp = j >> 3, i = j & 7;
    unsigned nm1 = (unsigned)(n - 1), Em1 = (unsigned)(E - 1);
    float bj = bias[j];

    int nw = gridDim.x * 4;
    for (int d = blockIdx.x * 4 + r; d < n; d += nw) {      // wave-uniform loop
        float dd = dinv[d];
        int k0 = row_start[d], k1 = row_start[d + 1];
        k1 = min(k1, E); k0 = max(min(k0, k1), 0);

        float a[8];
        agg_oct(gIn, bucket, k0, k1, d, a, j, nm1, Em1);

        // partials -> padded LDS rows (wave-local, in-order DS => no barrier)
        float4* prow = (float4*)&sVp[r][grp][8 * i];
        prow[0] = make_float4(a[0], a[1], a[2], a[3]);
        prow[1] = make_float4(a[4], a[5], a[6], a[7]);
        float full = 0.f;
#pragma unroll
        for (int g = 0; g < 8; ++g) full += sVp[r][g][j];   // 2-way bank: free

        float act = fmaxf(fmaf(dd, full, bj), 0.f);
        sVp[r][0][j] = act;               // reads above already issued (in-order)

        float acc0 = 0.f, acc1 = 0.f;
#pragma unroll
        for (int k4 = 0; k4 < 16; ++k4) {
            float4 av = *(const float4*)&sVp[r][0][4 * k4];   // broadcast b128
            unsigned wA = swpk[(2 * k4) * 64 + j];            // 2-way bank: free
            unsigned wB = swpk[(2 * k4 + 1) * 64 + j];
            acc0 = fmaf(av.x, __uint_as_float(wA << 16), acc0);
            acc1 = fmaf(av.y, __uint_as_float(wA & 0xffff0000u), acc1);
            acc0 = fmaf(av.z, __uint_as_float(wB << 16), acc0);
            acc1 = fmaf(av.w, __uint_as_float(wB & 0xffff0000u), acc1);
        }
        gOut[(size_t)d * 64 + j] = __float2bfloat16((acc0 + acc1) * dd);
    }
}

// Last hidden conv fused with 64->1 matmul (r21 verbatim):
// zg[d] = (relu(dd*sum+b) . Wout) * dd.
__global__ __launch_bounds__(TPB) void k_gconv_z(
    const bf16* __restrict__ gIn, const float* __restrict__ dinv,
    const int* __restrict__ row_start, const unsigned short* __restrict__ bucket,
    const float* __restrict__ bias, const float* __restrict__ Wout,
    float* __restrict__ zg, int n, int E) {
    __shared__ float sVp[4][8][68];
    int tid = threadIdx.x;
    int r = tid >> 6, j = tid & 63;
    int grp = j >> 3, i = j & 7;
    int d = blockIdx.x * 4 + r;
    if (d >= n) return;                   // wave-uniform (no barriers in kernel)
    float dd = dinv[d];
    int k0 = row_start[d], k1 = row_start[d + 1];
    k1 = min(k1, E); k0 = max(min(k0, k1), 0);

    float a[8];
    agg_oct(gIn, bucket, k0, k1, d, a, j, (unsigned)(n - 1), (unsigned)(E - 1));

    float4* prow = (float4*)&sVp[r][grp][8 * i];
    prow[0] = make_float4(a[0], a[1], a[2], a[3]);
    prow[1] = make_float4(a[4], a[5], a[6], a[7]);
    float full = 0.f;
#pragma unroll
    for (int g = 0; g < 8; ++g) full += sVp[r][g][j];

    float p = fmaxf(fmaf(dd, full, bias[j]), 0.f) * Wout[j];
#pragma unroll
    for (int off = 32; off > 0; off >>= 1) p += __shfl_down(p, off);
    if (j == 0) zg[d] = p * dd;
}

// out[d] = dd*(zg[d] + sum zg[s]) + b_out.  One wave per node, lane = edge slot.
__global__ __launch_bounds__(TPB) void k_out(
    const float* __restrict__ zg, const float* __restrict__ dinv,
    const int* __restrict__ row_start, const unsigned short* __restrict__ bucket,
    const float* __restrict__ b_out, float* __restrict__ out, int n, int E) {
    int t = blockIdx.x * blockDim.x + threadIdx.x;
    int d = t >> 6, lane = t & 63;
    if (d >= n) return;
    int k0 = row_start[d], k1 = row_start[d + 1];
    k1 = min(k1, E); k0 = max(min(k0, k1), 0);
    unsigned nm1 = (unsigned)(n - 1);
    float v = 0.f;
    for (int k = k0 + lane; k < k1; k += 64) {
        unsigned s = min((unsigned)bucket[k], nm1);
        v += zg[s];
    }
#pragma unroll
    for (int off = 32; off > 0; off >>= 1) v += __shfl_down(v, off);
    if (lane == 0) out[d] = fmaf(zg[d] + v, dinv[d], b_out[0]);
}

extern "C" void kernel_launch(void* const* d_in, const int* in_sizes, int n_in,
                              void* d_out, int out_size, void* d_ws, size_t ws_size,
                              hipStream_t stream) {
    const float* x     = (const float*)d_in[0];
    const int*   ei    = (const int*)d_in[1];
    const float* W_in  = (const float*)d_in[2];
    const float* b_in  = (const float*)d_in[3];
    const float* W_h   = (const float*)d_in[4];
    const float* b_h   = (const float*)d_in[5];
    const float* W_out = (const float*)d_in[6];
    const float* b_out = (const float*)d_in[7];
    float* out = (float*)d_out;

    int N = in_sizes[0] / 4;
    int E = in_sizes[1] / 2;
    const int* src = ei;
    const int* dst = ei + E;

    char* ws = (char*)d_ws;
    bf16* gA               = (bf16*)ws;           ws += (size_t)N * 64 * 2;
    bf16* gB               = (bf16*)ws;           ws += (size_t)N * 64 * 2;
    float4* xt             = (float4*)ws;         ws += (size_t)N * 16;
    unsigned short* bucket = (unsigned short*)ws; ws += (size_t)E * 2;
    unsigned* staging      = (unsigned*)ws;       ws += (size_t)E * 4;
    int*  row_start        = (int*)ws;            ws += (size_t)(N + 1) * 4;
    float* dinv            = (float*)ws;          ws += (size_t)N * 4;
    float* zg              = (float*)ws;          ws += (size_t)N * 4;
    unsigned* wpk          = (unsigned*)ws;       ws += 3 * 2048 * 4;
    int*  bktcnt           = (int*)ws;            ws += 256 * 4;
    int*  ticket           = (int*)ws;            ws += 4;
    int*  bktbase          = (int*)ws;            ws += 257 * 4;
    int*  bcur             = (int*)ws;            // 256 ints

    int B     = (N + 255) >> 8;          // dst buckets (196 for N=50000; <=256)
    int gN4   = (N + 3) / 4;             // 4 nodes/block (1 wave per node)
    int gP6   = 1536;                    // persistent grid, 6 blocks/CU
    int gP8   = 2048;                    // persistent grid, 8 blocks/CU
    int gBin  = (E + CHUNK - 1) / CHUNK; // 391

    // ---- CSR build + norms (bucket-centric; scan fused into count) ----
    k_zero_b<<<1, 256, 0, stream>>>(bktcnt, ticket);
    k_pack<<<24, TPB, 0, stream>>>(W_h, wpk);
    k_bktcnt<<<gBin, TPB, 0, stream>>>(dst, bktcnt, ticket, bktbase, bcur, E, N);
    k_bin<<<gBin, TPB, 0, stream>>>(src, dst, bcur, staging, E, N);
    k_unbin2<<<B, TPB, 0, stream>>>(staging, bktbase, x, xt, row_start, dinv, bucket, E, N);

    // ---- layers (feature buffers premultiplied by dinv) ----
    k_gconv1<<<gP8, TPB, 0, stream>>>(xt, dinv, row_start, bucket, W_in, b_in, wpk, gB, N, E);
    k_gconv<<<gP6, TPB, 0, stream>>>(gB, dinv, row_start, bucket, b_h, wpk + 2048, gA, N, E);
    k_gconv<<<gP6, TPB, 0, stream>>>(gA, dinv, row_start, bucket, b_h + 64, wpk + 4096, gB, N, E);
    k_gconv_z<<<gN4, TPB, 0, stream>>>(gB, dinv, row_start, bucket, b_h + 128, W_out, zg, N, E);
    k_out<<<gN4, TPB, 0, stream>>>(zg, dinv, row_start, bucket, b_out, out, N, E);
}

// Round 10
// 292.402 us; speedup vs baseline: 1.3873x; 1.3873x over previous
//
#include <hip/hip_runtime.h>
#include <hip/hip_bf16.h>

// GCN: N=50000, E=800000, hidden 64, 5 convs (relu on first 4).
// f32 tensors, int32 edge_index, f32 d_out[N].  ws_size in [19.8, 26.0) MB.
// r27: direct CSR. r22/r24/r25/r26 verdict: any occupancy demand >4 waves/SIMD
// makes the allocator spill (VGPR 64/40/40/32, WRITE 57-84MB scratch) — conv
// structure is frozen at r21's proven 259us config (all five compute kernels
// verbatim). This round's single variable: replace the 4-kernel bucket CSR
// (staging u32[E] double-pass + LDS histograms + double scans, est 60-85us) with
// a direct build: k_deg0 (zero) -> k_deg (800K L2 atomics on 200KB deg) ->
// k_scan1 (block sums + ticket-fused base scan) -> k_scan2 (block-local scan ->
// row_start/cur/dinv/xt) -> k_scat (pos=atomicAdd(cur[dst]); bucket[pos]=src).
// ~1/3 the memory work, no 3.2MB staging array. dst uniform-random over 50K
// addresses => no atomic hot spots.
// Tripwires: absmax ~6.1e-5; total -15us or CSR theory is dead.
// Workspace (~16.2 MB): gA bf16[N*64] | gB bf16[N*64] | xt f32x4[N] | bucket u16[E]
//   | row_start i32[N+1] | dinv f32[N] | zg f32[N] | deg i32[N] | cur i32[N]
//   | bsum i32[256] | bbase i32[257] | ticket i32

#define TPB 256
#define EPT 8                    // edges per thread in k_deg / k_scat
#define CHUNK (TPB * EPT)        // 2048 edges per block
typedef __hip_bfloat16 bf16;
#define B2F __bfloat162float

// ---- direct CSR build ----

__global__ void k_deg0(int* __restrict__ deg, int* __restrict__ ticket, int n) {
    int t = blockIdx.x * blockDim.x + threadIdx.x;
    if (t < n) deg[t] = 0;
    if (t == 0) *ticket = 0;
}

__global__ __launch_bounds__(TPB) void k_deg(
    const int* __restrict__ dst, int* __restrict__ deg, int E, int n) {
    int e0 = blockIdx.x * CHUNK + threadIdx.x;
#pragma unroll
    for (int u = 0; u < EPT; ++u) {
        int e = e0 + u * TPB;
        if (e < E) {
            int d = dst[e];
            if ((unsigned)d < (unsigned)n) atomicAdd(&deg[d], 1);
        }
    }
}

// Per-block sum of deg chunk -> bsum[b]; LAST block (ticket) scans bsum -> bbase
// (exclusive). Same fence/ticket/atomic-readback pattern as the proven k_bktcnt.
__global__ __launch_bounds__(TPB) void k_scan1(
    int* __restrict__ bsum, int* __restrict__ bbase, int* __restrict__ ticket,
    const int* __restrict__ deg, int n) {
    __shared__ int s[256];
    __shared__ int lastFlag;
    int b = blockIdx.x, tid = threadIdx.x;
    int nb = gridDim.x;
    int d = b * 256 + tid;
    int v = (d < n) ? deg[d] : 0;
    s[tid] = v;
    __syncthreads();
    for (int off = 128; off > 0; off >>= 1) {
        if (tid < off) s[tid] += s[tid + off];
        __syncthreads();
    }
    if (tid == 0) bsum[b] = s[0];
    __threadfence();
    __syncthreads();
    if (tid == 0) lastFlag = (atomicAdd(ticket, 1) == nb - 1);
    __syncthreads();
    if (!lastFlag) return;                         // block-uniform exit
    // last block: coherent read of block sums, exclusive scan (nb <= 256)
    int bv = (tid < nb) ? atomicAdd(&bsum[tid], 0) : 0;
    s[tid] = bv;
    __syncthreads();
    for (int off = 1; off < 256; off <<= 1) {
        int u2 = (tid >= off) ? s[tid - off] : 0;
        __syncthreads();
        s[tid] += u2;
        __syncthreads();
    }
    if (tid < nb) bbase[tid] = s[tid] - bv;        // exclusive base per block
    if (tid == nb - 1) bbase[nb] = s[tid];         // total valid edges
}

// Block-local exclusive scan + bbase -> row_start, cur, dinv, xt (=x*dinv).
__global__ __launch_bounds__(TPB) void k_scan2(
    const int* __restrict__ deg, const int* __restrict__ bbase,
    const float* __restrict__ x, float4* __restrict__ xt,
    int* __restrict__ row_start, float* __restrict__ dinv,
    int* __restrict__ cur, int n) {
    __shared__ int s[256];
    int b = blockIdx.x, tid = threadIdx.x;
    int d = b * 256 + tid;
    int v = (d < n) ? deg[d] : 0;
    s[tid] = v;
    __syncthreads();
    for (int off = 1; off < 256; off <<= 1) {
        int u2 = (tid >= off) ? s[tid - off] : 0;
        __syncthreads();
        s[tid] += u2;
        __syncthreads();
    }
    int base = bbase[b] + (s[tid] - v);            // global exclusive prefix
    if (d < n) {
        row_start[d] = base;
        cur[d] = base;
        float di = rsqrtf((float)v + 1.0f);        // +1 self-loop
        dinv[d] = di;
        float4 xv = ((const float4*)x)[d];         // x is f32[N][4], 16B aligned
        xv.x *= di; xv.y *= di; xv.z *= di; xv.w *= di;
        xt[d] = xv;                                // premultiplied raw features
        if (d == n - 1) row_start[n] = base + v;
    }
}

// Scatter edges: bucket[atomicAdd(cur[dst])] = src (u16; N < 65536).
__global__ __launch_bounds__(TPB) void k_scat(
    const int* __restrict__ src, const int* __restrict__ dst,
    int* __restrict__ cur, unsigned short* __restrict__ bucket, int E, int n) {
    int e0 = blockIdx.x * CHUNK + threadIdx.x;
#pragma unroll
    for (int u = 0; u < EPT; ++u) {
        int e = e0 + u * TPB;
        if (e < E) {
            int d = dst[e], s = src[e];
            if ((unsigned)d < (unsigned)n && (unsigned)s < (unsigned)n) {
                int pos = atomicAdd(&cur[d], 1);
                if ((unsigned)pos < (unsigned)E)   // replay-safe guard
                    bucket[pos] = (unsigned short)s;
            }
        }
    }
}

// ---- compute kernels: r21 verbatim (259.3us configuration) ----

__device__ __forceinline__ void acc_oct(float* a, uint4 w) {
    a[0] += __uint_as_float(w.x << 16);
    a[1] += __uint_as_float(w.x & 0xffff0000u);
    a[2] += __uint_as_float(w.y << 16);
    a[3] += __uint_as_float(w.y & 0xffff0000u);
    a[4] += __uint_as_float(w.z << 16);
    a[5] += __uint_as_float(w.z & 0xffff0000u);
    a[6] += __uint_as_float(w.w << 16);
    a[7] += __uint_as_float(w.w & 0xffff0000u);
}

// OCT gather (r17/r21 proven shape): 8 edges per load instruction. Lane group
// grp=lane>>3 takes edge k+grp; lane i=lane&7 loads uint4 = 8 packed bf16 feats
// (8 lanes x 16B = full 128B row). Partials in registers; caller combines across
// groups via padded LDS rows.
__device__ __forceinline__ void agg_oct(const bf16* __restrict__ g,
                                        const unsigned short* __restrict__ bucket,
                                        int k0, int k1, int d, float* __restrict__ a,
                                        int lane, unsigned nm1, unsigned Em1) {
    int grp = lane >> 3, i = lane & 7;
#pragma unroll
    for (int m = 0; m < 8; ++m) a[m] = 0.f;
    if (grp == 0) {  // self term
        uint4 w = *(const uint4*)(g + (size_t)d * 64 + 8 * i);
        acc_oct(a, w);
    }
    for (int base = k0; base < k1; base += 64) {
        int cnt = min(64, k1 - base);
        int rec = bucket[min((unsigned)(base + lane), Em1)];  // coalesced u16 load
        int k = 0;
        for (; k + 16 <= cnt; k += 16) {                      // 16 edges, 2 oct loads
            unsigned s0 = min((unsigned)__shfl(rec, k + grp), nm1);
            unsigned s1 = min((unsigned)__shfl(rec, k + 8 + grp), nm1);
            uint4 w0 = *(const uint4*)(g + (size_t)s0 * 64 + 8 * i);
            uint4 w1 = *(const uint4*)(g + (size_t)s1 * 64 + 8 * i);
            acc_oct(a, w0);
            acc_oct(a, w1);
        }
        for (; k < cnt; k += 8) {                             // tail, predicated
            int e = k + grp;
            unsigned s = min((unsigned)__shfl(rec, min(e, 63)), nm1);
            uint4 w = *(const uint4*)(g + (size_t)s * 64 + 8 * i);
            if (e < cnt) acc_oct(a, w);
        }
    }
}

// Layer 1, aggregate-first: agg4[d] = xt[d] + sum xt[s] (16B f32 rows, linearity
// of aggregation). Lane-parallel gather, butterfly reduce, 4-fma W_in transform,
// relu; persistent tail with W_h0 column in 64 VGPRs.
__global__ __launch_bounds__(TPB, 4) void k_gconv1(
    const float4* __restrict__ xt, const float* __restrict__ dinv,
    const int* __restrict__ row_start, const unsigned short* __restrict__ bucket,
    const float* __restrict__ W_in, const float* __restrict__ b_in,
    const float* __restrict__ Wh0, bf16* __restrict__ gOut, int n, int E) {
    __shared__ float sAct[4][64];
    int tid = threadIdx.x;
    int r = tid >> 6, j = tid & 63;
    unsigned nm1 = (unsigned)(n - 1);

    float wreg[64];
#pragma unroll
    for (int k = 0; k < 64; ++k) wreg[k] = Wh0[k * 64 + j];
    float win0 = W_in[0 * 64 + j], win1 = W_in[1 * 64 + j];
    float win2 = W_in[2 * 64 + j], win3 = W_in[3 * 64 + j];
    float bj = b_in[j];

    int nw = gridDim.x * 4;
    for (int d = blockIdx.x * 4 + r; d < n; d += nw) {      // wave-uniform loop
        float dd = dinv[d];
        int k0 = row_start[d], k1 = row_start[d + 1];
        k1 = min(k1, E); k0 = max(min(k0, k1), 0);

        float4 v = make_float4(0.f, 0.f, 0.f, 0.f);
        if (j == 0) v = xt[d];                              // self term
        for (int k = k0 + j; k < k1; k += 64) {
            unsigned s = min((unsigned)bucket[k], nm1);
            float4 t = xt[s];
            v.x += t.x; v.y += t.y; v.z += t.z; v.w += t.w;
        }
#pragma unroll
        for (int off = 1; off < 64; off <<= 1) {            // butterfly: all lanes
            v.x += __shfl_xor(v.x, off);
            v.y += __shfl_xor(v.y, off);
            v.z += __shfl_xor(v.z, off);
            v.w += __shfl_xor(v.w, off);
        }
        float dot = fmaf(v.x, win0, fmaf(v.y, win1, fmaf(v.z, win2, v.w * win3)));
        float act = fmaxf(fmaf(dd, dot, bj), 0.f);
        sAct[r][j] = act;                 // wave-local RAW -> lgkmcnt, no barrier

        float acc0 = 0.f, acc1 = 0.f, acc2 = 0.f, acc3 = 0.f;
        const float4* ap = (const float4*)&sAct[r][0];
#pragma unroll
        for (int k4 = 0; k4 < 16; ++k4) {
            float4 av = ap[k4];           // wave-uniform address -> broadcast b128
            acc0 = fmaf(av.x, wreg[4 * k4 + 0], acc0);
            acc1 = fmaf(av.y, wreg[4 * k4 + 1], acc1);
            acc2 = fmaf(av.z, wreg[4 * k4 + 2], acc2);
            acc3 = fmaf(av.w, wreg[4 * k4 + 3], acc3);
        }
        float acc = (acc0 + acc1) + (acc2 + acc3);
        gOut[(size_t)d * 64 + j] = __float2bfloat16(acc * dd);
    }
}

// Persistent fused middle layer (r21): grid-stride waves, W column in 64 VGPRs.
// Combine via padded partial rows sVp[wave][8][68]; act broadcast from LDS.
__global__ __launch_bounds__(TPB, 4) void k_gconv(
    const bf16* __restrict__ gIn, const float* __restrict__ dinv,
    const int* __restrict__ row_start, const unsigned short* __restrict__ bucket,
    const float* __restrict__ bias, const float* __restrict__ W,
    bf16* __restrict__ gOut, int n, int E) {
    __shared__ float sVp[4][8][68];      // 8704 B, padded
    int tid = threadIdx.x;
    int r = tid >> 6, j = tid & 63;
    int grp = j >> 3, i = j & 7;
    unsigned nm1 = (unsigned)(n - 1), Em1 = (unsigned)(E - 1);

    float wreg[64];
#pragma unroll
    for (int k = 0; k < 64; ++k) wreg[k] = W[k * 64 + j];   // coalesced per k
    float bj = bias[j];

    int nw = gridDim.x * 4;
    for (int d = blockIdx.x * 4 + r; d < n; d += nw) {      // wave-uniform loop
        float dd = dinv[d];
        int k0 = row_start[d], k1 = row_start[d + 1];
        k1 = min(k1, E); k0 = max(min(k0, k1), 0);

        float a[8];
        agg_oct(gIn, bucket, k0, k1, d, a, j, nm1, Em1);

        // partials -> padded LDS rows (wave-local, in-order DS => no barrier)
        float4* prow = (float4*)&sVp[r][grp][8 * i];
        prow[0] = make_float4(a[0], a[1], a[2], a[3]);
        prow[1] = make_float4(a[4], a[5], a[6], a[7]);
        float full = 0.f;
#pragma unroll
        for (int g = 0; g < 8; ++g) full += sVp[r][g][j];   // 2-way bank: free

        float act = fmaxf(fmaf(dd, full, bj), 0.f);
        sVp[r][0][j] = act;               // reads above already issued (in-order)

        float acc0 = 0.f, acc1 = 0.f, acc2 = 0.f, acc3 = 0.f;
#pragma unroll
        for (int k4 = 0; k4 < 16; ++k4) {
            float4 av = *(const float4*)&sVp[r][0][4 * k4];   // broadcast b128
            acc0 = fmaf(av.x, wreg[4 * k4 + 0], acc0);
            acc1 = fmaf(av.y, wreg[4 * k4 + 1], acc1);
            acc2 = fmaf(av.z, wreg[4 * k4 + 2], acc2);
            acc3 = fmaf(av.w, wreg[4 * k4 + 3], acc3);
        }
        float acc = (acc0 + acc1) + (acc2 + acc3);
        gOut[(size_t)d * 64 + j] = __float2bfloat16(acc * dd);
    }
}

// Last hidden conv fused with 64->1 matmul (r21 verbatim):
// zg[d] = (relu(dd*sum+b) . Wout) * dd.
__global__ __launch_bounds__(TPB) void k_gconv_z(
    const bf16* __restrict__ gIn, const float* __restrict__ dinv,
    const int* __restrict__ row_start, const unsigned short* __restrict__ bucket,
    const float* __restrict__ bias, const float* __restrict__ Wout,
    float* __restrict__ zg, int n, int E) {
    __shared__ float sVp[4][8][68];
    int tid = threadIdx.x;
    int r = tid >> 6, j = tid & 63;
    int grp = j >> 3, i = j & 7;
    int d = blockIdx.x * 4 + r;
    if (d >= n) return;                   // wave-uniform (no barriers in kernel)
    float dd = dinv[d];
    int k0 = row_start[d], k1 = row_start[d + 1];
    k1 = min(k1, E); k0 = max(min(k0, k1), 0);

    float a[8];
    agg_oct(gIn, bucket, k0, k1, d, a, j, (unsigned)(n - 1), (unsigned)(E - 1));

    float4* prow = (float4*)&sVp[r][grp][8 * i];
    prow[0] = make_float4(a[0], a[1], a[2], a[3]);
    prow[1] = make_float4(a[4], a[5], a[6], a[7]);
    float full = 0.f;
#pragma unroll
    for (int g = 0; g < 8; ++g) full += sVp[r][g][j];

    float p = fmaxf(fmaf(dd, full, bias[j]), 0.f) * Wout[j];
#pragma unroll
    for (int off = 32; off > 0; off >>= 1) p += __shfl_down(p, off);
    if (j == 0) zg[d] = p * dd;
}

// out[d] = dd*(zg[d] + sum zg[s]) + b_out.  One wave per node, lane = edge slot.
__global__ __launch_bounds__(TPB) void k_out(
    const float* __restrict__ zg, const float* __restrict__ dinv,
    const int* __restrict__ row_start, const unsigned short* __restrict__ bucket,
    const float* __restrict__ b_out, float* __restrict__ out, int n, int E) {
    int t = blockIdx.x * blockDim.x + threadIdx.x;
    int d = t >> 6, lane = t & 63;
    if (d >= n) return;
    int k0 = row_start[d], k1 = row_start[d + 1];
    k1 = min(k1, E); k0 = max(min(k0, k1), 0);
    unsigned nm1 = (unsigned)(n - 1);
    float v = 0.f;
    for (int k = k0 + lane; k < k1; k += 64) {
        unsigned s = min((unsigned)bucket[k], nm1);
        v += zg[s];
    }
#pragma unroll
    for (int off = 32; off > 0; off >>= 1) v += __shfl_down(v, off);
    if (lane == 0) out[d] = fmaf(zg[d] + v, dinv[d], b_out[0]);
}

extern "C" void kernel_launch(void* const* d_in, const int* in_sizes, int n_in,
                              void* d_out, int out_size, void* d_ws, size_t ws_size,
                              hipStream_t stream) {
    const float* x     = (const float*)d_in[0];
    const int*   ei    = (const int*)d_in[1];
    const float* W_in  = (const float*)d_in[2];
    const float* b_in  = (const float*)d_in[3];
    const float* W_h   = (const float*)d_in[4];
    const float* b_h   = (const float*)d_in[5];
    const float* W_out = (const float*)d_in[6];
    const float* b_out = (const float*)d_in[7];
    float* out = (float*)d_out;

    int N = in_sizes[0] / 4;
    int E = in_sizes[1] / 2;
    const int* src = ei;
    const int* dst = ei + E;

    char* ws = (char*)d_ws;
    bf16* gA               = (bf16*)ws;           ws += (size_t)N * 64 * 2;
    bf16* gB               = (bf16*)ws;           ws += (size_t)N * 64 * 2;
    float4* xt             = (float4*)ws;         ws += (size_t)N * 16;
    unsigned short* bucket = (unsigned short*)ws; ws += (size_t)E * 2;
    int*  row_start        = (int*)ws;            ws += (size_t)(N + 1) * 4;
    float* dinv            = (float*)ws;          ws += (size_t)N * 4;
    float* zg              = (float*)ws;          ws += (size_t)N * 4;
    int*  deg              = (int*)ws;            ws += (size_t)N * 4;
    int*  cur              = (int*)ws;            ws += (size_t)N * 4;
    int*  bsum             = (int*)ws;            ws += 256 * 4;
    int*  bbase            = (int*)ws;            ws += 257 * 4;
    int*  ticket           = (int*)ws;            // 1 int

    int nbN   = (N + 255) >> 8;          // 196 blocks over nodes
    int gN4   = (N + 3) / 4;             // 4 nodes/block (1 wave per node)
    int gPers = 1024;                    // persistent conv grid (4 blocks/CU)
    int gE    = (E + CHUNK - 1) / CHUNK; // 391 blocks over edges

    // ---- direct CSR build + norms ----
    k_deg0<<<nbN, TPB, 0, stream>>>(deg, ticket, N);
    k_deg<<<gE, TPB, 0, stream>>>(dst, deg, E, N);
    k_scan1<<<nbN, TPB, 0, stream>>>(bsum, bbase, ticket, deg, N);
    k_scan2<<<nbN, TPB, 0, stream>>>(deg, bbase, x, xt, row_start, dinv, cur, N);
    k_scat<<<gE, TPB, 0, stream>>>(src, dst, cur, bucket, E, N);

    // ---- layers (feature buffers premultiplied by dinv) ----
    k_gconv1<<<gPers, TPB, 0, stream>>>(xt, dinv, row_start, bucket, W_in, b_in, W_h, gB, N, E);
    k_gconv<<<gPers, TPB, 0, stream>>>(gB, dinv, row_start, bucket, b_h, W_h + 4096, gA, N, E);
    k_gconv<<<gPers, TPB, 0, stream>>>(gA, dinv, row_start, bucket, b_h + 64, W_h + 8192, gB, N, E);
    k_gconv_z<<<gN4, TPB, 0, stream>>>(gB, dinv, row_start, bucket, b_h + 128, W_out, zg, N, E);
    k_out<<<gN4, TPB, 0, stream>>>(zg, dinv, row_start, bucket, b_out, out, N, E);
}

// Round 11
// 291.628 us; speedup vs baseline: 1.3909x; 1.0027x over previous
//
#include <hip/hip_runtime.h>
#include <hip/hip_bf16.h>

// GCN: N=50000, E=800000, hidden 64, 5 convs (relu on first 4).
// f32 tensors, int32 edge_index, f32 d_out[N].  ws_size in [19.8, 26.0) MB.
// r28: dual-node gather WITHOUT register-W. Spill ledger: r22 dual+wreg (146 reg)
// spilled; r24/r25 wreg-packed at 6w/SIMD spilled; r26 LDS-W at cap-64 spilled.
// Untested cell: dual-node + LDS-W(f32,16KB) + (256,4)/cap-128 -> est 80-90 VGPR,
// no spill. Doubles in-flight gather loads/wave (2 bucket + 4 oct) at unchanged
// wave count. r27's direct CSR lost (+33us) -> bucket CSR restored (r21 verbatim).
// Applied to k_gconv x2 + k_gconv_z (persistent dual, no W). gconv1/k_out = r21.
// Tripwires: conv WRITE_SIZE ~6.3MB & VGPR 80-105 (spill detector).
// Workspace (~19.0 MB): gA bf16[N*64] | gB bf16[N*64] | xt f32x4[N] | bucket u16[E]
//   | staging u32[E] | row_start i32[N+1] | dinv f32[N] | zg f32[N] | bktcnt i32[256]
//   | ticket i32 | bktbase i32[257] | bcur i32[256]

#define TPB 256
#define EPT 8                    // edges per thread in k_bktcnt / k_bin
#define CHUNK (TPB * EPT)        // 2048 edges per block
typedef __hip_bfloat16 bf16;
#define B2F __bfloat162float

__global__ void k_zero_b(int* __restrict__ bktcnt, int* __restrict__ ticket) {
    bktcnt[threadIdx.x] = 0;
    if (threadIdx.x == 0) *ticket = 0;
}

// Per-bucket (dst>>8) edge counts via LDS histogram; LAST block (ticket) also
// performs the 256-wide exclusive scan -> bktbase[257], bcur (fuses k_bktscan).
__global__ __launch_bounds__(TPB) void k_bktcnt(
    const int* __restrict__ dst, int* __restrict__ bktcnt, int* __restrict__ ticket,
    int* __restrict__ bktbase, int* __restrict__ bcur, int E, int n) {
    __shared__ int h[256];
    __shared__ int lastFlag;
    int tid = threadIdx.x;
    h[tid] = 0;
    __syncthreads();
    int e0 = blockIdx.x * CHUNK;
#pragma unroll
    for (int u = 0; u < EPT; ++u) {
        int e = e0 + u * TPB + tid;
        if (e < E) {
            int d = dst[e];
            if ((unsigned)d < (unsigned)n) atomicAdd(&h[d >> 8], 1);
        }
    }
    __syncthreads();
    if (h[tid]) atomicAdd(&bktcnt[tid], h[tid]);
    __threadfence();                               // counts visible before ticket
    __syncthreads();
    if (tid == 0) lastFlag = (atomicAdd(ticket, 1) == (int)gridDim.x - 1);
    __syncthreads();
    if (!lastFlag) return;                         // block-uniform exit
    // last block: coherent read of final counts, then scan (reuse h as buffer)
    int v = atomicAdd(&bktcnt[tid], 0);
    h[tid] = v;
    __syncthreads();
    for (int off = 1; off < 256; off <<= 1) {
        int u2 = (tid >= off) ? h[tid - off] : 0;
        __syncthreads();
        h[tid] += u2;
        __syncthreads();
    }
    int excl = h[tid] - v;
    bktbase[tid] = excl;
    bcur[tid] = excl;
    if (tid == 255) bktbase[256] = h[tid];
}

// Pass 1: bin edges by dst>>8 into staging (record = src | (dst&255)<<16).
__global__ __launch_bounds__(TPB) void k_bin(
    const int* __restrict__ src, const int* __restrict__ dst,
    int* __restrict__ bcur, unsigned* __restrict__ staging, int E, int n) {
    __shared__ int hcnt[256];
    __shared__ int hbase[256];
    int tid = threadIdx.x;
    int e0 = blockIdx.x * CHUNK;
    hcnt[tid] = 0;
    __syncthreads();

    int eb[EPT];
    unsigned rec[EPT];
#pragma unroll
    for (int u = 0; u < EPT; ++u) {
        int e = e0 + u * TPB + tid;
        eb[u] = -1;
        if (e < E) {
            int d = dst[e], s = src[e];
            if ((unsigned)d < (unsigned)n && (unsigned)s < (unsigned)n) {
                eb[u] = d >> 8;
                rec[u] = (unsigned)s | ((unsigned)(d & 255) << 16);
                atomicAdd(&hcnt[eb[u]], 1);
            }
        }
    }
    __syncthreads();
    int c = hcnt[tid];
    hbase[tid] = (c > 0) ? atomicAdd(&bcur[tid], c) : 0;
    hcnt[tid] = 0;
    __syncthreads();
#pragma unroll
    for (int u = 0; u < EPT; ++u) {
        if (eb[u] >= 0) {
            int r = atomicAdd(&hcnt[eb[u]], 1);
            int pos = hbase[eb[u]] + r;
            if ((unsigned)pos < (unsigned)E) staging[pos] = rec[u];  // replay-safe
        }
    }
}

// Pass 2: one block per bucket. Per-node histogram + prefix in LDS -> row_start,
// dinv, xt (=x*dinv), and record placement via LDS cursors.
__global__ __launch_bounds__(TPB) void k_unbin2(
    const unsigned* __restrict__ staging, const int* __restrict__ bktbase,
    const float* __restrict__ x, float4* __restrict__ xt,
    int* __restrict__ row_start, float* __restrict__ dinv,
    unsigned short* __restrict__ bucket, int E, int n) {
    __shared__ int cnt[256];
    __shared__ int scn[256];
    __shared__ int cur[256];
    int b = blockIdx.x, tid = threadIdx.x;
    int lo = bktbase[b], hi = bktbase[b + 1];
    lo = max(0, min(lo, E)); hi = max(lo, min(hi, E));

    cnt[tid] = 0;
    __syncthreads();
    for (int i = lo + tid; i < hi; i += TPB)
        atomicAdd(&cnt[(staging[i] >> 16) & 255], 1);
    __syncthreads();

    int v = cnt[tid];
    scn[tid] = v;
    __syncthreads();
    for (int off = 1; off < 256; off <<= 1) {
        int u = (tid >= off) ? scn[tid - off] : 0;
        __syncthreads();
        scn[tid] += u;
        __syncthreads();
    }
    int excl = scn[tid] - v;
    int base = min(lo + excl, E);
    cur[tid] = base;
    int d = (b << 8) + tid;
    if (d < n) {
        row_start[d] = base;
        float di = rsqrtf((float)v + 1.0f);    // +1 self-loop
        dinv[d] = di;
        float4 xv = ((const float4*)x)[d];     // x is f32[N][4], 16B aligned
        xv.x *= di; xv.y *= di; xv.z *= di; xv.w *= di;
        xt[d] = xv;                            // premultiplied raw features
        if (d == n - 1) row_start[n] = min(base + v, E);
    }
    __syncthreads();

    for (int i = lo + tid; i < hi; i += TPB) {
        unsigned r = staging[i];
        int t = (r >> 16) & 255;
        int pos = atomicAdd(&cur[t], 1);
        if ((unsigned)pos < (unsigned)E) bucket[pos] = (unsigned short)(r & 0xffffu);
    }
}

__device__ __forceinline__ void acc_oct(float* a, uint4 w) {
    a[0] += __uint_as_float(w.x << 16);
    a[1] += __uint_as_float(w.x & 0xffff0000u);
    a[2] += __uint_as_float(w.y << 16);
    a[3] += __uint_as_float(w.y & 0xffff0000u);
    a[4] += __uint_as_float(w.z << 16);
    a[5] += __uint_as_float(w.z & 0xffff0000u);
    a[6] += __uint_as_float(w.w << 16);
    a[7] += __uint_as_float(w.w & 0xffff0000u);
}

// Single-node chunk remainder: edges [kstart,cnt) of one 64-edge chunk.
__device__ __forceinline__ void agg_chunk(const bf16* __restrict__ g, int rec,
                                          int kstart, int cnt, float* __restrict__ a,
                                          int grp, int i, unsigned nm1) {
    int k = kstart;
    for (; k + 16 <= cnt; k += 16) {
        unsigned s0 = min((unsigned)__shfl(rec, k + grp), nm1);
        unsigned s1 = min((unsigned)__shfl(rec, k + 8 + grp), nm1);
        uint4 w0 = *(const uint4*)(g + (size_t)s0 * 64 + 8 * i);
        uint4 w1 = *(const uint4*)(g + (size_t)s1 * 64 + 8 * i);
        acc_oct(a, w0);
        acc_oct(a, w1);
    }
    for (; k < cnt; k += 8) {                              // tail, predicated
        int e = k + grp;
        unsigned s = min((unsigned)__shfl(rec, min(e, 63)), nm1);
        uint4 w = *(const uint4*)(g + (size_t)s * 64 + 8 * i);
        if (e < cnt) acc_oct(a, w);
    }
}

// Dual-node OCT gather (r22's shape, proven correct): nodes A and B with a FUSED
// inner loop — per chunk pair, 2 independent bucket loads then 4 independent oct
// feat loads in flight (2x memory parallelism on the latency-critical path).
__device__ __forceinline__ void agg_oct2(const bf16* __restrict__ g,
                                         const unsigned short* __restrict__ bucket,
                                         int k0a, int k1a, int da,
                                         int k0b, int k1b, int db, bool hasB,
                                         float* __restrict__ aA, float* __restrict__ aB,
                                         int lane, unsigned nm1, unsigned Em1) {
    int grp = lane >> 3, i = lane & 7;
#pragma unroll
    for (int m = 0; m < 8; ++m) { aA[m] = 0.f; aB[m] = 0.f; }
    if (grp == 0) {  // self terms (independent loads)
        uint4 wa = *(const uint4*)(g + (size_t)da * 64 + 8 * i);
        acc_oct(aA, wa);
        if (hasB) {
            uint4 wb = *(const uint4*)(g + (size_t)db * 64 + 8 * i);
            acc_oct(aB, wb);
        }
    }
    int bA = k0a, bB = k0b;
    while (bA < k1a && bB < k1b) {        // fused chunk pair (wave-uniform)
        int cA = min(64, k1a - bA), cB = min(64, k1b - bB);
        int recA = bucket[min((unsigned)(bA + lane), Em1)];
        int recB = bucket[min((unsigned)(bB + lane), Em1)];
        int cm = min(cA, cB);
        int k = 0;
        for (; k + 16 <= cm; k += 16) {   // 4 independent oct loads in flight
            unsigned s0a = min((unsigned)__shfl(recA, k + grp), nm1);
            unsigned s1a = min((unsigned)__shfl(recA, k + 8 + grp), nm1);
            unsigned s0b = min((unsigned)__shfl(recB, k + grp), nm1);
            unsigned s1b = min((unsigned)__shfl(recB, k + 8 + grp), nm1);
            uint4 w0a = *(const uint4*)(g + (size_t)s0a * 64 + 8 * i);
            uint4 w1a = *(const uint4*)(g + (size_t)s1a * 64 + 8 * i);
            uint4 w0b = *(const uint4*)(g + (size_t)s0b * 64 + 8 * i);
            uint4 w1b = *(const uint4*)(g + (size_t)s1b * 64 + 8 * i);
            acc_oct(aA, w0a);
            acc_oct(aA, w1a);
            acc_oct(aB, w0b);
            acc_oct(aB, w1b);
        }
        agg_chunk(g, recA, k, cA, aA, grp, i, nm1);   // A remainder of this chunk
        agg_chunk(g, recB, k, cB, aB, grp, i, nm1);   // B remainder of this chunk
        bA += 64; bB += 64;
    }
    for (; bA < k1a; bA += 64) {          // A-only leftover chunks
        int cA = min(64, k1a - bA);
        int recA = bucket[min((unsigned)(bA + lane), Em1)];
        agg_chunk(g, recA, 0, cA, aA, grp, i, nm1);
    }
    for (; bB < k1b; bB += 64) {          // B-only leftover chunks
        int cB = min(64, k1b - bB);
        int recB = bucket[min((unsigned)(bB + lane), Em1)];
        agg_chunk(g, recB, 0, cB, aB, grp, i, nm1);
    }
}

// Layer 1, aggregate-first (r21 verbatim): agg4[d] = xt[d] + sum xt[s].
__global__ __launch_bounds__(TPB, 4) void k_gconv1(
    const float4* __restrict__ xt, const float* __restrict__ dinv,
    const int* __restrict__ row_start, const unsigned short* __restrict__ bucket,
    const float* __restrict__ W_in, const float* __restrict__ b_in,
    const float* __restrict__ Wh0, bf16* __restrict__ gOut, int n, int E) {
    __shared__ float sAct[4][64];
    int tid = threadIdx.x;
    int r = tid >> 6, j = tid & 63;
    unsigned nm1 = (unsigned)(n - 1);

    float wreg[64];
#pragma unroll
    for (int k = 0; k < 64; ++k) wreg[k] = Wh0[k * 64 + j];
    float win0 = W_in[0 * 64 + j], win1 = W_in[1 * 64 + j];
    float win2 = W_in[2 * 64 + j], win3 = W_in[3 * 64 + j];
    float bj = b_in[j];

    int nw = gridDim.x * 4;
    for (int d = blockIdx.x * 4 + r; d < n; d += nw) {      // wave-uniform loop
        float dd = dinv[d];
        int k0 = row_start[d], k1 = row_start[d + 1];
        k1 = min(k1, E); k0 = max(min(k0, k1), 0);

        float4 v = make_float4(0.f, 0.f, 0.f, 0.f);
        if (j == 0) v = xt[d];                              // self term
        for (int k = k0 + j; k < k1; k += 64) {
            unsigned s = min((unsigned)bucket[k], nm1);
            float4 t = xt[s];
            v.x += t.x; v.y += t.y; v.z += t.z; v.w += t.w;
        }
#pragma unroll
        for (int off = 1; off < 64; off <<= 1) {            // butterfly: all lanes
            v.x += __shfl_xor(v.x, off);
            v.y += __shfl_xor(v.y, off);
            v.z += __shfl_xor(v.z, off);
            v.w += __shfl_xor(v.w, off);
        }
        float dot = fmaf(v.x, win0, fmaf(v.y, win1, fmaf(v.z, win2, v.w * win3)));
        float act = fmaxf(fmaf(dd, dot, bj), 0.f);
        sAct[r][j] = act;                 // wave-local RAW -> lgkmcnt, no barrier

        float acc0 = 0.f, acc1 = 0.f, acc2 = 0.f, acc3 = 0.f;
        const float4* ap = (const float4*)&sAct[r][0];
#pragma unroll
        for (int k4 = 0; k4 < 16; ++k4) {
            float4 av = ap[k4];           // wave-uniform address -> broadcast b128
            acc0 = fmaf(av.x, wreg[4 * k4 + 0], acc0);
            acc1 = fmaf(av.y, wreg[4 * k4 + 1], acc1);
            acc2 = fmaf(av.z, wreg[4 * k4 + 2], acc2);
            acc3 = fmaf(av.w, wreg[4 * k4 + 3], acc3);
        }
        float acc = (acc0 + acc1) + (acc2 + acc3);
        gOut[(size_t)d * 64 + j] = __float2bfloat16(acc * dd);
    }
}

// Persistent fused middle layer, DUAL-NODE + LDS-W: W f32 staged once per block
// (16KB, one barrier before the persistent loop); each wave-iteration gathers
// nodes 2p,2p+1 with the fused agg_oct2 (2x in-flight loads), then combines and
// transforms each via wave-local padded sVp rows (no further barriers). No W
// registers -> est 80-90 VGPR at the proven (256,4) cap, no spill.
__global__ __launch_bounds__(TPB, 4) void k_gconv(
    const bf16* __restrict__ gIn, const float* __restrict__ dinv,
    const int* __restrict__ row_start, const unsigned short* __restrict__ bucket,
    const float* __restrict__ bias, const float* __restrict__ W,
    bf16* __restrict__ gOut, int n, int E) {
    __shared__ float sW[4096];           // 16 KB f32 W
    __shared__ float sVp[4][8][68];      // 8.7 KB, padded
    int tid = threadIdx.x;
    {   // cooperative W stage (all threads, before the single barrier)
        const float4* W4 = (const float4*)W;
        float4* sW4 = (float4*)sW;
#pragma unroll
        for (int t = 0; t < 4; ++t) sW4[tid + t * 256] = W4[tid + t * 256];
    }
    __syncthreads();

    int r = tid >> 6, j = tid & 63;
    int grp = j >> 3, i = j & 7;
    unsigned nm1 = (unsigned)(n - 1), Em1 = (unsigned)(E - 1);
    float bj = bias[j];

    int nw = gridDim.x * 4;
    int npair = (n + 1) >> 1;
    for (int p = blockIdx.x * 4 + r; p < npair; p += nw) {  // wave-uniform loop
        int dA = 2 * p, dB = dA + 1;
        bool hasB = dB < n;
        float ddA = dinv[dA];
        int k0a = row_start[dA], k1a = row_start[dA + 1];
        k1a = min(k1a, E); k0a = max(min(k0a, k1a), 0);
        float ddB = 0.f;
        int k0b = 0, k1b = 0;
        if (hasB) {
            ddB = dinv[dB];
            k0b = row_start[dB]; k1b = row_start[dB + 1];
            k1b = min(k1b, E); k0b = max(min(k0b, k1b), 0);
        }

        float aA[8], aB[8];
        agg_oct2(gIn, bucket, k0a, k1a, dA, k0b, k1b, min(dB, n - 1), hasB,
                 aA, aB, j, nm1, Em1);

        // ---- node A: combine + transform (wave-local, in-order DS) ----
        float4* prow = (float4*)&sVp[r][grp][8 * i];
        prow[0] = make_float4(aA[0], aA[1], aA[2], aA[3]);
        prow[1] = make_float4(aA[4], aA[5], aA[6], aA[7]);
        float full = 0.f;
#pragma unroll
        for (int g = 0; g < 8; ++g) full += sVp[r][g][j];   // 2-way bank: free
        float act = fmaxf(fmaf(ddA, full, bj), 0.f);
        sVp[r][0][j] = act;               // reads above already issued (in-order)
        float acc0 = 0.f, acc1 = 0.f, acc2 = 0.f, acc3 = 0.f;
#pragma unroll
        for (int k4 = 0; k4 < 16; ++k4) {
            float4 av = *(const float4*)&sVp[r][0][4 * k4];   // broadcast b128
            acc0 = fmaf(av.x, sW[(4 * k4 + 0) * 64 + j], acc0);
            acc1 = fmaf(av.y, sW[(4 * k4 + 1) * 64 + j], acc1);
            acc2 = fmaf(av.z, sW[(4 * k4 + 2) * 64 + j], acc2);
            acc3 = fmaf(av.w, sW[(4 * k4 + 3) * 64 + j], acc3);
        }
        gOut[(size_t)dA * 64 + j] = __float2bfloat16(((acc0 + acc1) + (acc2 + acc3)) * ddA);

        // ---- node B (sVp row reuse safe: in-order wave-local DS) ----
        if (hasB) {
            prow[0] = make_float4(aB[0], aB[1], aB[2], aB[3]);
            prow[1] = make_float4(aB[4], aB[5], aB[6], aB[7]);
            float fullB = 0.f;
#pragma unroll
            for (int g = 0; g < 8; ++g) fullB += sVp[r][g][j];
            float actB = fmaxf(fmaf(ddB, fullB, bj), 0.f);
            sVp[r][0][j] = actB;
            float b0 = 0.f, b1 = 0.f, b2 = 0.f, b3 = 0.f;
#pragma unroll
            for (int k4 = 0; k4 < 16; ++k4) {
                float4 av = *(const float4*)&sVp[r][0][4 * k4];
                b0 = fmaf(av.x, sW[(4 * k4 + 0) * 64 + j], b0);
                b1 = fmaf(av.y, sW[(4 * k4 + 1) * 64 + j], b1);
                b2 = fmaf(av.z, sW[(4 * k4 + 2) * 64 + j], b2);
                b3 = fmaf(av.w, sW[(4 * k4 + 3) * 64 + j], b3);
            }
            gOut[(size_t)dB * 64 + j] = __float2bfloat16(((b0 + b1) + (b2 + b3)) * ddB);
        }
    }
}

// Last hidden conv fused with 64->1 matmul, persistent DUAL-NODE (no W matrix):
// zg[d] = (relu(dd*sum+b) . Wout) * dd.  r22's shape (it did not spill).
__global__ __launch_bounds__(TPB, 4) void k_gconv_z(
    const bf16* __restrict__ gIn, const float* __restrict__ dinv,
    const int* __restrict__ row_start, const unsigned short* __restrict__ bucket,
    const float* __restrict__ bias, const float* __restrict__ Wout,
    float* __restrict__ zg, int n, int E) {
    __shared__ float sVp[4][8][68];
    int tid = threadIdx.x;
    int r = tid >> 6, j = tid & 63;
    int grp = j >> 3, i = j & 7;
    unsigned nm1 = (unsigned)(n - 1), Em1 = (unsigned)(E - 1);
    float bj = bias[j], wj = Wout[j];

    int nw = gridDim.x * 4;
    int npair = (n + 1) >> 1;
    for (int p = blockIdx.x * 4 + r; p < npair; p += nw) {  // wave-uniform loop
        int dA = 2 * p, dB = dA + 1;
        bool hasB = dB < n;
        float ddA = dinv[dA];
        int k0a = row_start[dA], k1a = row_start[dA + 1];
        k1a = min(k1a, E); k0a = max(min(k0a, k1a), 0);
        float ddB = 0.f;
        int k0b = 0, k1b = 0;
        if (hasB) {
            ddB = dinv[dB];
            k0b = row_start[dB]; k1b = row_start[dB + 1];
            k1b = min(k1b, E); k0b = max(min(k0b, k1b), 0);
        }

        float aA[8], aB[8];
        agg_oct2(gIn, bucket, k0a, k1a, dA, k0b, k1b, min(dB, n - 1), hasB,
                 aA, aB, j, nm1, Em1);

        float4* prow = (float4*)&sVp[r][grp][8 * i];
        prow[0] = make_float4(aA[0], aA[1], aA[2], aA[3]);
        prow[1] = make_float4(aA[4], aA[5], aA[6], aA[7]);
        float full = 0.f;
#pragma unroll
        for (int g = 0; g < 8; ++g) full += sVp[r][g][j];
        float pA = fmaxf(fmaf(ddA, full, bj), 0.f) * wj;
#pragma unroll
        for (int off = 32; off > 0; off >>= 1) pA += __shfl_down(pA, off);
        if (j == 0) zg[dA] = pA * ddA;

        if (hasB) {
            prow[0] = make_float4(aB[0], aB[1], aB[2], aB[3]);
            prow[1] = make_float4(aB[4], aB[5], aB[6], aB[7]);
            float fullB = 0.f;
#pragma unroll
            for (int g = 0; g < 8; ++g) fullB += sVp[r][g][j];
            float pB = fmaxf(fmaf(ddB, fullB, bj), 0.f) * wj;
#pragma unroll
            for (int off = 32; off > 0; off >>= 1) pB += __shfl_down(pB, off);
            if (j == 0) zg[dB] = pB * ddB;
        }
    }
}

// out[d] = dd*(zg[d] + sum zg[s]) + b_out.  One wave per node, lane = edge slot.
__global__ __launch_bounds__(TPB) void k_out(
    const float* __restrict__ zg, const float* __restrict__ dinv,
    const int* __restrict__ row_start, const unsigned short* __restrict__ bucket,
    const float* __restrict__ b_out, float* __restrict__ out, int n, int E) {
    int t = blockIdx.x * blockDim.x + threadIdx.x;
    int d = t >> 6, lane = t & 63;
    if (d >= n) return;
    int k0 = row_start[d], k1 = row_start[d + 1];
    k1 = min(k1, E); k0 = max(min(k0, k1), 0);
    unsigned nm1 = (unsigned)(n - 1);
    float v = 0.f;
    for (int k = k0 + lane; k < k1; k += 64) {
        unsigned s = min((unsigned)bucket[k], nm1);
        v += zg[s];
    }
#pragma unroll
    for (int off = 32; off > 0; off >>= 1) v += __shfl_down(v, off);
    if (lane == 0) out[d] = fmaf(zg[d] + v, dinv[d], b_out[0]);
}

extern "C" void kernel_launch(void* const* d_in, const int* in_sizes, int n_in,
                              void* d_out, int out_size, void* d_ws, size_t ws_size,
                              hipStream_t stream) {
    const float* x     = (const float*)d_in[0];
    const int*   ei    = (const int*)d_in[1];
    const float* W_in  = (const float*)d_in[2];
    const float* b_in  = (const float*)d_in[3];
    const float* W_h   = (const float*)d_in[4];
    const float* b_h   = (const float*)d_in[5];
    const float* W_out = (const float*)d_in[6];
    const float* b_out = (const float*)d_in[7];
    float* out = (float*)d_out;

    int N = in_sizes[0] / 4;
    int E = in_sizes[1] / 2;
    const int* src = ei;
    const int* dst = ei + E;

    char* ws = (char*)d_ws;
    bf16* gA               = (bf16*)ws;           ws += (size_t)N * 64 * 2;
    bf16* gB               = (bf16*)ws;           ws += (size_t)N * 64 * 2;
    float4* xt             = (float4*)ws;         ws += (size_t)N * 16;
    unsigned short* bucket = (unsigned short*)ws; ws += (size_t)E * 2;
    unsigned* staging      = (unsigned*)ws;       ws += (size_t)E * 4;
    int*  row_start        = (int*)ws;            ws += (size_t)(N + 1) * 4;
    float* dinv            = (float*)ws;          ws += (size_t)N * 4;
    float* zg              = (float*)ws;          ws += (size_t)N * 4;
    int*  bktcnt           = (int*)ws;            ws += 256 * 4;
    int*  ticket           = (int*)ws;            ws += 4;
    int*  bktbase          = (int*)ws;            ws += 257 * 4;
    int*  bcur             = (int*)ws;            // 256 ints

    int B     = (N + 255) >> 8;          // dst buckets (196 for N=50000; <=256)
    int gN4   = (N + 3) / 4;             // 4 nodes/block (1 wave per node)
    int gPers = 1024;                    // persistent conv grid (4 blocks/CU)
    int gBin  = (E + CHUNK - 1) / CHUNK; // 391

    // ---- CSR build + norms (bucket-centric; scan fused into count) ----
    k_zero_b<<<1, 256, 0, stream>>>(bktcnt, ticket);
    k_bktcnt<<<gBin, TPB, 0, stream>>>(dst, bktcnt, ticket, bktbase, bcur, E, N);
    k_bin<<<gBin, TPB, 0, stream>>>(src, dst, bcur, staging, E, N);
    k_unbin2<<<B, TPB, 0, stream>>>(staging, bktbase, x, xt, row_start, dinv, bucket, E, N);

    // ---- layers (feature buffers premultiplied by dinv) ----
    k_gconv1<<<gPers, TPB, 0, stream>>>(xt, dinv, row_start, bucket, W_in, b_in, W_h, gB, N, E);
    k_gconv<<<gPers, TPB, 0, stream>>>(gB, dinv, row_start, bucket, b_h, W_h + 4096, gA, N, E);
    k_gconv<<<gPers, TPB, 0, stream>>>(gA, dinv, row_start, bucket, b_h + 64, W_h + 8192, gB, N, E);
    k_gconv_z<<<gPers, TPB, 0, stream>>>(gB, dinv, row_start, bucket, b_h + 128, W_out, zg, N, E);
    k_out<<<gN4, TPB, 0, stream>>>(zg, dinv, row_start, bucket, b_out, out, N, E);
}